// Round 2
// baseline (10088.390 us; speedup 1.0000x reference)
//
#include <hip/hip_runtime.h>
#include <cmath>

#define SEQ 2048
#define NB 64            // batch
#define VOC 128
#define DM 2176
#define NEG_INF -1e30f

// ------------------------------------------------------------------
// Generic tiled f32 GEMM.  C[M,N] = A[M,K] @ B  (TB=0: B[K,N], TB=1: C=A@B^T with B[N,K])
// M,N multiples of 64; K multiple of 16.
// ------------------------------------------------------------------
template<int TB>
__global__ __launch_bounds__(256) void gemm_f32(
    const float* __restrict__ A, int lda,
    const float* __restrict__ B, int ldb,
    float* __restrict__ C, int ldc,
    int M, int N, int K)
{
    __shared__ float As[16][64];
    __shared__ float Bs[16][65];
    const int bm = blockIdx.y * 64;
    const int bn = blockIdx.x * 64;
    const int t  = threadIdx.x;
    const int tx = t & 15, ty = t >> 4;
    float acc[4][4] = {};
    for (int k0 = 0; k0 < K; k0 += 16) {
        #pragma unroll
        for (int i = 0; i < 4; ++i) {
            int m = (t >> 4) + 16 * i;
            int k = t & 15;
            As[k][m] = A[(size_t)(bm + m) * lda + k0 + k];
        }
        if (TB == 0) {
            #pragma unroll
            for (int i = 0; i < 4; ++i) {
                int n = t & 63;
                int k = (t >> 6) + 4 * i;
                Bs[k][n] = B[(size_t)(k0 + k) * ldb + bn + n];
            }
        } else {
            #pragma unroll
            for (int i = 0; i < 4; ++i) {
                int k = t & 15;
                int n = (t >> 4) + 16 * i;
                Bs[k][n] = B[(size_t)(bn + n) * ldb + k0 + k];
            }
        }
        __syncthreads();
        #pragma unroll
        for (int kk = 0; kk < 16; ++kk) {
            float a[4], bb[4];
            #pragma unroll
            for (int i = 0; i < 4; ++i) a[i] = As[kk][ty * 4 + i];
            #pragma unroll
            for (int j = 0; j < 4; ++j) bb[j] = Bs[kk][tx * 4 + j];
            #pragma unroll
            for (int i = 0; i < 4; ++i)
                #pragma unroll
                for (int j = 0; j < 4; ++j)
                    acc[i][j] += a[i] * bb[j];
        }
        __syncthreads();
    }
    #pragma unroll
    for (int i = 0; i < 4; ++i) {
        size_t m = bm + ty * 4 + i;
        #pragma unroll
        for (int j = 0; j < 4; ++j)
            C[m * ldc + bn + tx * 4 + j] = acc[i][j];
    }
}

// ------------------------------------------------------------------
// Core: per (batch, 16-query tile) flash attention where scores come
// from 4 precomputed tables; accumulates O = A1 @ [TvK[tok]+VpK | TvV[tok]+VpV]
// O is [64, 2048, 256] f32.
// ------------------------------------------------------------------
#define QB 16
#define KBT 32

__global__ __launch_bounds__(256) void attn_core(
    const int* __restrict__ tok,
    const float* __restrict__ Gtt, const float* __restrict__ Gtk,
    const float* __restrict__ Gqt, const float* __restrict__ Gqk,
    const float* __restrict__ TvK, const float* __restrict__ TvV,
    const float* __restrict__ VpK, const float* __restrict__ VpV,
    const float* __restrict__ beta1,
    float* __restrict__ O)
{
    const int b  = blockIdx.y;
    const int q0 = blockIdx.x * QB;
    const int t  = threadIdx.x;
    const float c1 = beta1[0] * 1.12890625f;   // (2176/2048)^2

    __shared__ float M_s[KBT][256];
    __shared__ float P_s[QB][36];              // padded, rows 16B-aligned
    __shared__ float m_s[QB], l_s[QB], rs_s[QB];
    __shared__ int   tq_s[QB], tk_s[KBT];

    if (t < QB) {
        tq_s[t] = tok[(size_t)b * SEQ + q0 + t];
        m_s[t]  = NEG_INF;
        l_s[t]  = 0.f;
    }
    float acc[QB];
    #pragma unroll
    for (int i = 0; i < QB; ++i) acc[i] = 0.f;

    const int kend = q0 + QB;
    for (int k0 = 0; k0 < kend; k0 += KBT) {
        if (t < KBT) tk_s[t] = tok[(size_t)b * SEQ + k0 + t];
        __syncthreads();

        // build value tile M_s[k][c]
        if (t < 128) {
            const int c = t;
            #pragma unroll 4
            for (int k = 0; k < KBT; ++k)
                M_s[k][c] = TvK[tk_s[k] * 128 + c] + VpK[(size_t)(k0 + k) * 128 + c];
        } else {
            const int c = t - 128;
            #pragma unroll 4
            for (int k = 0; k < KBT; ++k)
                M_s[k][t] = TvV[tk_s[k] * 128 + c] + VpV[(size_t)(k0 + k) * 128 + c];
        }
        // raw scores: 512 (q,k) pairs, 2 per thread
        #pragma unroll
        for (int pp = 0; pp < 2; ++pp) {
            int p = t + pp * 256;
            int q = p >> 5, k = p & 31;
            int qg = q0 + q, kg = k0 + k;
            float s = NEG_INF;
            if (kg <= qg) {
                int tq = tq_s[q], tk = tk_s[k];
                s = c1 * (Gtt[tq * 128 + tk] + Gtk[(size_t)tq * SEQ + kg]
                        + Gqt[qg * 128 + tk] + Gqk[(size_t)qg * SEQ + kg]);
            }
            P_s[q][k] = s;
        }
        __syncthreads();

        // online softmax row update (16 threads)
        if (t < QB) {
            float m_old = m_s[t];
            float tmax  = m_old;
            #pragma unroll 8
            for (int k = 0; k < KBT; ++k) tmax = fmaxf(tmax, P_s[t][k]);
            float rs = __expf(m_old - tmax);
            float lsum = 0.f;
            #pragma unroll 8
            for (int k = 0; k < KBT; ++k) {
                float e = __expf(P_s[t][k] - tmax);
                P_s[t][k] = e;
                lsum += e;
            }
            m_s[t]  = tmax;
            l_s[t]  = l_s[t] * rs + lsum;
            rs_s[t] = rs;
        }
        __syncthreads();

        // rescale + accumulate; thread t owns output column t
        #pragma unroll
        for (int q = 0; q < QB; ++q) acc[q] *= rs_s[q];
        #pragma unroll 2
        for (int k4 = 0; k4 < KBT; k4 += 4) {
            float mv0 = M_s[k4 + 0][t];
            float mv1 = M_s[k4 + 1][t];
            float mv2 = M_s[k4 + 2][t];
            float mv3 = M_s[k4 + 3][t];
            #pragma unroll
            for (int q = 0; q < QB; ++q) {
                float4 p = *(const float4*)&P_s[q][k4];
                acc[q] += p.x * mv0 + p.y * mv1 + p.z * mv2 + p.w * mv3;
            }
        }
        __syncthreads();
    }
    #pragma unroll
    for (int q = 0; q < QB; ++q) {
        float inv = 1.f / l_s[q];
        O[((size_t)b * SEQ + q0 + q) * 256 + t] = acc[q] * inv;
    }
}

// ------------------------------------------------------------------
// Stage 2: one 256-thread workgroup per batch.
// ------------------------------------------------------------------
__device__ __forceinline__ float blk_reduce_max(float v, float* red, int t)
{
    red[t] = v; __syncthreads();
    #pragma unroll
    for (int s = 128; s >= 1; s >>= 1) {
        if (t < s) red[t] = fmaxf(red[t], red[t + s]);
        __syncthreads();
    }
    float r = red[0]; __syncthreads(); return r;
}
__device__ __forceinline__ float blk_reduce_sum(float v, float* red, int t)
{
    red[t] = v; __syncthreads();
    #pragma unroll
    for (int s = 128; s >= 1; s >>= 1) {
        if (t < s) red[t] += red[t + s];
        __syncthreads();
    }
    float r = red[0]; __syncthreads(); return r;
}

__global__ __launch_bounds__(256) void stage2(
    const int* __restrict__ tok,
    const float* __restrict__ emb, const float* __restrict__ pos,
    const float* __restrict__ Gtt, const float* __restrict__ Gtk,
    const float* __restrict__ Gqt, const float* __restrict__ Gqk,
    const float* __restrict__ Tv,  const float* __restrict__ Vp,
    const float* __restrict__ WQ2,
    const float* __restrict__ TxK, const float* __restrict__ PxK,
    const float* __restrict__ TxV, const float* __restrict__ PxV,
    const float* __restrict__ O,
    const float* __restrict__ beta1, const float* __restrict__ beta2,
    const float* __restrict__ beta_out,
    float* __restrict__ out)
{
    const int b = blockIdx.x;
    const int t = threadIdx.x;
    const float c1 = beta1[0] * 1.12890625f;
    const float c2 = beta2[0] * 289.0f;                  // (2176/128)^2
    const float co = beta_out[0] * 70.09279563550022f;   // 17^1.5

    __shared__ float a_s[SEQ];
    __shared__ float red_s[256];
    __shared__ float w_s[VOC];
    __shared__ float z_s[DM];
    __shared__ float q2_s[VOC];
    __shared__ float y2_s[VOC];

    const int* tokb = tok + (size_t)b * SEQ;
    const int tq = tokb[SEQ - 1];

    // ---- last-row stage-1 attention weights ----
    float lmax = NEG_INF;
    for (int i = t; i < SEQ; i += 256) {
        int tk = tokb[i];
        float s = c1 * (Gtt[tq * 128 + tk] + Gtk[(size_t)tq * SEQ + i]
                      + Gqt[(SEQ - 1) * 128 + tk] + Gqk[(size_t)(SEQ - 1) * SEQ + i]);
        a_s[i] = s;
        lmax = fmaxf(lmax, s);
    }
    float m = blk_reduce_max(lmax, red_s, t);
    float lsum = 0.f;
    for (int i = t; i < SEQ; i += 256) {
        float e = __expf(a_s[i] - m);
        a_s[i] = e;
        lsum += e;
    }
    float l = blk_reduce_sum(lsum, red_s, t);
    float inv = 1.f / l;
    for (int i = t; i < SEQ; i += 256) a_s[i] *= inv;

    // ---- token-aggregated weights ----
    if (t < VOC) w_s[t] = 0.f;
    __syncthreads();
    for (int i = t; i < SEQ; i += 256) {
        int tk = tokb[i];
        atomicAdd(&w_s[tk], a_s[i]);
    }
    __syncthreads();

    // ---- Z1 last row (full 2176 dims) ----
    float accz[9];
    #pragma unroll
    for (int j = 0; j < 9; ++j) accz[j] = 0.f;
    for (int k = 0; k < SEQ; ++k) {
        float a = a_s[k];
        const float* vr = Vp + (size_t)k * DM;
        #pragma unroll
        for (int j = 0; j < 9; ++j) {
            int d = t + j * 256;
            if (d < DM) accz[j] += a * vr[d];
        }
    }
    for (int tt = 0; tt < VOC; ++tt) {
        float w = w_s[tt];
        const float* tr = Tv + (size_t)tt * DM;
        #pragma unroll
        for (int j = 0; j < 9; ++j) {
            int d = t + j * 256;
            if (d < DM) accz[j] += w * tr[d];
        }
    }
    #pragma unroll
    for (int j = 0; j < 9; ++j) {
        int d = t + j * 256;
        if (d < DM) {
            float x = (d < VOC) ? emb[tq * VOC + d]
                                : pos[(size_t)(SEQ - 1) * SEQ + (d - VOC)];
            z_s[d] = x + accz[j];
        }
    }
    __syncthreads();

    // ---- q2 = Z1_last @ WQ2  (fold in c2) ----
    if (t < VOC) {
        float s = 0.f;
        for (int d = 0; d < DM; ++d) s += z_s[d] * WQ2[(size_t)d * VOC + t];
        q2_s[t] = c2 * s;
    }
    __syncthreads();

    // ---- S2 over all positions ----
    float lmax2 = NEG_INF;
    for (int i = t; i < SEQ; i += 256) {
        int tk = tokb[i];
        const float* orow = O + ((size_t)b * SEQ + i) * 256;
        const float* xk = TxK + tk * VOC;
        const float* pk = PxK + (size_t)i * VOC;
        float s = 0.f;
        for (int v = 0; v < VOC; ++v) s += q2_s[v] * (xk[v] + pk[v] + orow[v]);
        a_s[i] = s;
        lmax2 = fmaxf(lmax2, s);
    }
    float m2 = blk_reduce_max(lmax2, red_s, t);
    float lsum2 = 0.f;
    for (int i = t; i < SEQ; i += 256) {
        float e = __expf(a_s[i] - m2);
        a_s[i] = e;
        lsum2 += e;
    }
    float l2 = blk_reduce_sum(lsum2, red_s, t);
    float inv2 = 1.f / l2;
    for (int i = t; i < SEQ; i += 256) a_s[i] *= inv2;
    __syncthreads();

    // ---- Y2 ----
    if (t < VOC) {
        float y = 0.f;
        for (int s2 = 0; s2 < SEQ; ++s2) {
            int tk = tokb[s2];
            y += a_s[s2] * (TxV[tk * VOC + t] + PxV[(size_t)s2 * VOC + t]
                          + O[((size_t)b * SEQ + s2) * 256 + 128 + t]);
        }
        y2_s[t] = y;
    }
    __syncthreads();

    // ---- logits = co * Y2 @ emb^T ----
    if (t < VOC) {
        float g = 0.f;
        for (int v = 0; v < VOC; ++v) g += y2_s[v] * emb[t * VOC + v];
        out[(size_t)b * VOC + t] = co * g;
    }
}

// ------------------------------------------------------------------
extern "C" void kernel_launch(void* const* d_in, const int* in_sizes, int n_in,
                              void* d_out, int out_size, void* d_ws, size_t ws_size,
                              hipStream_t stream)
{
    const int* tok = (const int*)d_in[0];          // int64 ref input delivered as int32
    const float* emb = (const float*)d_in[1];
    const float* pos = (const float*)d_in[2];
    const float* WQ1 = (const float*)d_in[3];
    const float* WK1 = (const float*)d_in[4];
    const float* WV1 = (const float*)d_in[5];
    const float* WQ2 = (const float*)d_in[6];
    const float* WK2 = (const float*)d_in[7];
    const float* WV2 = (const float*)d_in[8];
    const float* beta1 = (const float*)d_in[9];
    const float* beta2 = (const float*)d_in[10];
    const float* beta_out = (const float*)d_in[11];
    float* out = (float*)d_out;
    float* ws  = (float*)d_ws;

    const size_t needed = 53051392ull;           // floats (~202.4 MB)
    if (ws_size < needed * sizeof(float)) return; // clean fail if ws too small

    size_t off = 0;
    auto take = [&](size_t n) { float* p = ws + off; off += n; return p; };
    float* Tq  = take((size_t)128 * 2048);
    float* Tk  = take((size_t)128 * 2048);
    float* Tv  = take((size_t)128 * 2176);
    float* Qp  = take((size_t)2048 * 2048);
    float* Kp  = take((size_t)2048 * 2048);
    float* Vp  = take((size_t)2048 * 2176);
    float* Gqk = take((size_t)2048 * 2048);
    float* Gtk = take((size_t)128 * 2048);
    float* Gqt = take((size_t)2048 * 128);
    float* Gtt = take((size_t)128 * 128);
    float* TvK = take((size_t)128 * 128);
    float* TvV = take((size_t)128 * 128);
    float* TxK = take((size_t)128 * 128);
    float* TxV = take((size_t)128 * 128);
    float* VpK = take((size_t)2048 * 128);
    float* VpV = take((size_t)2048 * 128);
    float* PxK = take((size_t)2048 * 128);
    float* PxV = take((size_t)2048 * 128);
    float* O   = take((size_t)64 * 2048 * 256);

    dim3 blk(256);
    auto g = [](int N, int M) { return dim3(N / 64, M / 64); };

    // token tables (K = 128 rows of stage-1 weights)
    hipLaunchKernelGGL((gemm_f32<0>), g(2048, 128), blk, 0, stream, emb, 128, WQ1, 2048, Tq, 2048, 128, 2048, 128);
    hipLaunchKernelGGL((gemm_f32<0>), g(2048, 128), blk, 0, stream, emb, 128, WK1, 2048, Tk, 2048, 128, 2048, 128);
    hipLaunchKernelGGL((gemm_f32<0>), g(2176, 128), blk, 0, stream, emb, 128, WV1, 2176, Tv, 2176, 128, 2176, 128);
    // positional tables
    hipLaunchKernelGGL((gemm_f32<0>), g(2048, 2048), blk, 0, stream, pos, 2048, WQ1 + (size_t)128 * 2048, 2048, Qp, 2048, 2048, 2048, 2048);
    hipLaunchKernelGGL((gemm_f32<0>), g(2048, 2048), blk, 0, stream, pos, 2048, WK1 + (size_t)128 * 2048, 2048, Kp, 2048, 2048, 2048, 2048);
    hipLaunchKernelGGL((gemm_f32<0>), g(2176, 2048), blk, 0, stream, pos, 2048, WV1 + (size_t)128 * 2176, 2176, Vp, 2176, 2048, 2176, 2048);
    // stage-2 X-part tables
    hipLaunchKernelGGL((gemm_f32<0>), g(128, 128),  blk, 0, stream, emb, 128, WK2, 128, TxK, 128, 128, 128, 128);
    hipLaunchKernelGGL((gemm_f32<0>), g(128, 128),  blk, 0, stream, emb, 128, WV2, 128, TxV, 128, 128, 128, 128);
    hipLaunchKernelGGL((gemm_f32<0>), g(128, 2048), blk, 0, stream, pos, 2048, WK2 + (size_t)128 * 128, 128, PxK, 128, 2048, 128, 2048);
    hipLaunchKernelGGL((gemm_f32<0>), g(128, 2048), blk, 0, stream, pos, 2048, WV2 + (size_t)128 * 128, 128, PxV, 128, 2048, 128, 2048);
    // score tables (need Qp,Kp,Tq,Tk)
    hipLaunchKernelGGL((gemm_f32<1>), g(2048, 2048), blk, 0, stream, Qp, 2048, Kp, 2048, Gqk, 2048, 2048, 2048, 2048);
    hipLaunchKernelGGL((gemm_f32<1>), g(2048, 128),  blk, 0, stream, Tq, 2048, Kp, 2048, Gtk, 2048, 128, 2048, 2048);
    hipLaunchKernelGGL((gemm_f32<1>), g(128, 2048),  blk, 0, stream, Qp, 2048, Tk, 2048, Gqt, 128, 2048, 128, 2048);
    hipLaunchKernelGGL((gemm_f32<1>), g(128, 128),   blk, 0, stream, Tq, 2048, Tk, 2048, Gtt, 128, 128, 128, 2048);
    // value projections through WK2/WV2 (need Vp,Tv)
    hipLaunchKernelGGL((gemm_f32<0>), g(128, 2048), blk, 0, stream, Vp, 2176, WK2, 128, VpK, 128, 2048, 128, 2176);
    hipLaunchKernelGGL((gemm_f32<0>), g(128, 2048), blk, 0, stream, Vp, 2176, WV2, 128, VpV, 128, 2048, 128, 2176);
    hipLaunchKernelGGL((gemm_f32<0>), g(128, 128),  blk, 0, stream, Tv, 2176, WK2, 128, TvK, 128, 128, 128, 2176);
    hipLaunchKernelGGL((gemm_f32<0>), g(128, 128),  blk, 0, stream, Tv, 2176, WV2, 128, TvV, 128, 128, 128, 2176);

    // core attention
    hipLaunchKernelGGL(attn_core, dim3(SEQ / QB, NB), blk, 0, stream,
                       tok, Gtt, Gtk, Gqt, Gqk, TvK, TvV, VpK, VpV, beta1, O);

    // stage 2
    hipLaunchKernelGGL(stage2, dim3(NB), blk, 0, stream,
                       tok, emb, pos, Gtt, Gtk, Gqt, Gqk, Tv, Vp, WQ2,
                       TxK, PxK, TxV, PxV, O, beta1, beta2, beta_out, out);
}

// Round 3
// 5487.502 us; speedup vs baseline: 1.8384x; 1.8384x over previous
//
#include <hip/hip_runtime.h>
#include <cmath>

#define SEQ 2048
#define NB 64
#define VOC 128
#define DM 2176
#define NEG_INF -1e30f

typedef __attribute__((ext_vector_type(8))) short short8;
typedef __attribute__((ext_vector_type(4))) float f32x4;
typedef __attribute__((ext_vector_type(4))) unsigned int uint4v;
typedef __attribute__((ext_vector_type(2))) unsigned int uint2v;

// ---------- bf16 split helpers (hi = truncation, lo = remainder) ----------
__device__ __forceinline__ void splitf(float x, unsigned short& h, unsigned short& l) {
    unsigned int u = __float_as_uint(x);
    h = (unsigned short)(u >> 16);
    float d = x - __uint_as_float(u & 0xFFFF0000u);
    l = (unsigned short)(__float_as_uint(d) >> 16);
}
__device__ __forceinline__ unsigned int bfpair(float x0, float x1, unsigned int& lopair) {
    unsigned int u0 = __float_as_uint(x0), u1 = __float_as_uint(x1);
    float d0 = x0 - __uint_as_float(u0 & 0xFFFF0000u);
    float d1 = x1 - __uint_as_float(u1 & 0xFFFF0000u);
    lopair = (__float_as_uint(d0) >> 16) | (__float_as_uint(d1) & 0xFFFF0000u);
    return (u0 >> 16) | (u1 & 0xFFFF0000u);
}

// ------------------------------------------------------------------
// Naive tiled f32 GEMM (kept for tiny token-table GEMMs).
// C[M,N] = A[M,K] @ B[K,N]. M,N mult of 64; K mult of 16.
// ------------------------------------------------------------------
template<int TB>
__global__ __launch_bounds__(256) void gemm_f32(
    const float* __restrict__ A, int lda,
    const float* __restrict__ B, int ldb,
    float* __restrict__ C, int ldc,
    int M, int N, int K)
{
    __shared__ float As[16][64];
    __shared__ float Bs[16][65];
    const int bm = blockIdx.y * 64;
    const int bn = blockIdx.x * 64;
    const int t  = threadIdx.x;
    const int tx = t & 15, ty = t >> 4;
    float acc[4][4] = {};
    for (int k0 = 0; k0 < K; k0 += 16) {
        #pragma unroll
        for (int i = 0; i < 4; ++i) {
            int m = (t >> 4) + 16 * i;
            int k = t & 15;
            As[k][m] = A[(size_t)(bm + m) * lda + k0 + k];
        }
        if (TB == 0) {
            #pragma unroll
            for (int i = 0; i < 4; ++i) {
                int n = t & 63;
                int k = (t >> 6) + 4 * i;
                Bs[k][n] = B[(size_t)(k0 + k) * ldb + bn + n];
            }
        } else {
            #pragma unroll
            for (int i = 0; i < 4; ++i) {
                int k = t & 15;
                int n = (t >> 4) + 16 * i;
                Bs[k][n] = B[(size_t)(bn + n) * ldb + k0 + k];
            }
        }
        __syncthreads();
        #pragma unroll
        for (int kk = 0; kk < 16; ++kk) {
            float a[4], bb[4];
            #pragma unroll
            for (int i = 0; i < 4; ++i) a[i] = As[kk][ty * 4 + i];
            #pragma unroll
            for (int j = 0; j < 4; ++j) bb[j] = Bs[kk][tx * 4 + j];
            #pragma unroll
            for (int i = 0; i < 4; ++i)
                #pragma unroll
                for (int j = 0; j < 4; ++j)
                    acc[i][j] += a[i] * bb[j];
        }
        __syncthreads();
    }
    #pragma unroll
    for (int i = 0; i < 4; ++i) {
        size_t m = bm + ty * 4 + i;
        #pragma unroll
        for (int j = 0; j < 4; ++j)
            C[m * ldc + bn + tx * 4 + j] = acc[i][j];
    }
}

// ------------------------------------------------------------------
// Split f32 -> (hi,lo) bf16, plain layout. n4 = element count / 4.
// ------------------------------------------------------------------
__global__ __launch_bounds__(256) void split_plain(
    const float* __restrict__ in, unsigned short* __restrict__ oh,
    unsigned short* __restrict__ ol, int n4)
{
    int i = blockIdx.x * 256 + threadIdx.x;
    if (i >= n4) return;
    f32x4 v = *(const f32x4*)(in + (size_t)i * 4);
    unsigned int h01, h23, l01, l23;
    h01 = bfpair(v[0], v[1], l01);
    h23 = bfpair(v[2], v[3], l23);
    *(uint2v*)(oh + (size_t)i * 4) = (uint2v){h01, h23};
    *(uint2v*)(ol + (size_t)i * 4) = (uint2v){l01, l23};
}

// ------------------------------------------------------------------
// Split + transpose: out[c][r] = in[(row0+r)*ld + c], r<NR, c<NC.
// out leading dim = NR. Grid (NR/32, NC/32), 256 threads.
// ------------------------------------------------------------------
__global__ __launch_bounds__(256) void splitT(
    const float* __restrict__ in, int ld, int row0,
    int NR, int NC,
    unsigned short* __restrict__ oh, unsigned short* __restrict__ ol)
{
    __shared__ float tile[32][33];
    const int r0 = blockIdx.x * 32, c0 = blockIdx.y * 32;
    const int t = threadIdx.x;
    const int x = t & 31, y = t >> 5;
    #pragma unroll
    for (int i = 0; i < 4; ++i) {
        int r = y + i * 8;
        tile[r][x] = in[(size_t)(row0 + r0 + r) * ld + c0 + x];
    }
    __syncthreads();
    #pragma unroll
    for (int i = 0; i < 4; ++i) {
        int c = y + i * 8;
        float v = tile[x][c];
        unsigned short h, l;
        splitf(v, h, l);
        size_t o = (size_t)(c0 + c) * NR + r0 + x;
        oh[o] = h; ol[o] = l;
    }
}

// ------------------------------------------------------------------
// Split-bf16 MFMA GEMM (NT): C[M,N] = (Ah+Al)[M,K] @ (Bh+Bl)[N,K]^T
// 3-term: AhBh + AhBl + AlBh. Tile 128x128, BK=64, 4 waves (2x2).
// MODE bit0: write f32 C; bit1: write split Ch/Cl.
// Grid: (N/128, M/128), 256 threads.
// ------------------------------------------------------------------
template<int MODE>
__global__ __launch_bounds__(256, 2) void gemm_nt_mfma(
    const unsigned short* __restrict__ Ah, const unsigned short* __restrict__ Al, int lda,
    const unsigned short* __restrict__ Bh, const unsigned short* __restrict__ Bl, int ldb,
    float* __restrict__ C, unsigned short* __restrict__ Ch, unsigned short* __restrict__ Cl,
    int ldc, int K)
{
    __shared__ __align__(16) unsigned short sAh[128 * 64], sAl[128 * 64];
    __shared__ __align__(16) unsigned short sBh[128 * 64], sBl[128 * 64];
    const int bm = blockIdx.y * 128, bn = blockIdx.x * 128;
    const int t = threadIdx.x;
    const int lane = t & 63, wave = t >> 6;
    const int wr = wave >> 1, wc = wave & 1;
    const int lr = lane & 15;

    f32x4 acc[4][4];
    #pragma unroll
    for (int i = 0; i < 4; ++i)
        #pragma unroll
        for (int j = 0; j < 4; ++j) acc[i][j] = (f32x4){0.f, 0.f, 0.f, 0.f};

    for (int k0 = 0; k0 < K; k0 += 64) {
        __syncthreads();
        #pragma unroll
        for (int i = 0; i < 4; ++i) {
            int idx = t + i * 256;
            int r = idx >> 3, kc = (idx & 7) * 8;
            int off = (r * 128 + kc * 2) ^ ((r & 7) << 4);
            size_t ga = (size_t)(bm + r) * lda + k0 + kc;
            size_t gb = (size_t)(bn + r) * ldb + k0 + kc;
            *(short8*)((char*)sAh + off) = *(const short8*)(Ah + ga);
            *(short8*)((char*)sAl + off) = *(const short8*)(Al + ga);
            *(short8*)((char*)sBh + off) = *(const short8*)(Bh + gb);
            *(short8*)((char*)sBl + off) = *(const short8*)(Bl + gb);
        }
        __syncthreads();
        #pragma unroll
        for (int ks = 0; ks < 2; ++ks) {
            const int kby = ks * 64 + ((lane >> 4) << 4);
            short8 ah[4], al[4];
            #pragma unroll
            for (int rf = 0; rf < 4; ++rf) {
                int row = wr * 64 + rf * 16 + lr;
                int off = (row * 128 + kby) ^ ((row & 7) << 4);
                ah[rf] = *(const short8*)((const char*)sAh + off);
                al[rf] = *(const short8*)((const char*)sAl + off);
            }
            #pragma unroll
            for (int cf = 0; cf < 4; ++cf) {
                int col = wc * 64 + cf * 16 + lr;
                int off = (col * 128 + kby) ^ ((col & 7) << 4);
                short8 bh = *(const short8*)((const char*)sBh + off);
                short8 bl = *(const short8*)((const char*)sBl + off);
                #pragma unroll
                for (int rf = 0; rf < 4; ++rf) {
                    acc[rf][cf] = __builtin_amdgcn_mfma_f32_16x16x32_bf16(ah[rf], bh, acc[rf][cf], 0, 0, 0);
                    acc[rf][cf] = __builtin_amdgcn_mfma_f32_16x16x32_bf16(ah[rf], bl, acc[rf][cf], 0, 0, 0);
                    acc[rf][cf] = __builtin_amdgcn_mfma_f32_16x16x32_bf16(al[rf], bh, acc[rf][cf], 0, 0, 0);
                }
            }
        }
    }
    #pragma unroll
    for (int rf = 0; rf < 4; ++rf) {
        #pragma unroll
        for (int j = 0; j < 4; ++j) {
            int row = bm + wr * 64 + rf * 16 + ((lane >> 4) << 2) + j;
            #pragma unroll
            for (int cf = 0; cf < 4; ++cf) {
                int col = bn + wc * 64 + cf * 16 + lr;
                float v = acc[rf][cf][j];
                size_t o = (size_t)row * ldc + col;
                if (MODE & 1) C[o] = v;
                if (MODE & 2) { unsigned short h, l; splitf(v, h, l); Ch[o] = h; Cl[o] = l; }
            }
        }
    }
}

// ------------------------------------------------------------------
// MFMA attention core. 64 queries/block, 32-wide K tiles, 4 waves each
// owning 64 of the 256 output columns. Scores from 4 precomputed f32
// tables; P and M split to bf16 hi/lo; 3-term MFMA PV accumulation.
// O[b][s][256] f32. Grid (SEQ/64, NB), 256 threads.
// ------------------------------------------------------------------
__global__ __launch_bounds__(256, 2) void attn_mfma(
    const int* __restrict__ tok,
    const float* __restrict__ Gtt, const float* __restrict__ Gtk,
    const float* __restrict__ Gqt, const float* __restrict__ Gqk,
    const float* __restrict__ TvK, const float* __restrict__ TvV,
    const float* __restrict__ VpK, const float* __restrict__ VpV,
    const float* __restrict__ beta1,
    float* __restrict__ O)
{
    const int b = blockIdx.y;
    const int q0 = blockIdx.x * 64;
    const int t = threadIdx.x;
    const int lane = t & 63, wave = t >> 6;
    const float c1 = beta1[0] * 1.12890625f;

    __shared__ __align__(16) unsigned short Mh[256 * 32], Ml[256 * 32];
    __shared__ __align__(16) unsigned short Ph[64 * 32], Pl[64 * 32];
    __shared__ __align__(16) float m_s[64], l_s[64], rs_s[64];
    __shared__ int tq_s[64], tk_s[32];

    if (t < 64) {
        tq_s[t] = tok[(size_t)b * SEQ + q0 + t];
        m_s[t] = NEG_INF;
        l_s[t] = 0.f;
    }
    f32x4 acc[4][4];
    #pragma unroll
    for (int i = 0; i < 4; ++i)
        #pragma unroll
        for (int j = 0; j < 4; ++j) acc[i][j] = (f32x4){0.f, 0.f, 0.f, 0.f};

    const int qr = t >> 3;
    const int kb4 = (t & 7) * 4;
    const int lr = lane & 15;
    const int kbyte = (lane >> 4) << 4;
    const int cbuild = t & 127;
    const float* Tb = (t < 128) ? TvK : TvV;
    const float* Vb = (t < 128) ? VpK : VpV;

    for (int k0 = 0; k0 <= q0 + 32; k0 += 32) {
        if (t < 32) tk_s[t] = tok[(size_t)b * SEQ + k0 + t];
        __syncthreads();
        // ---- build split M in [c][k] layout (thread t owns column t) ----
        #pragma unroll
        for (int g = 0; g < 4; ++g) {
            unsigned int hh[4], ll[4];
            #pragma unroll
            for (int p = 0; p < 4; ++p) {
                int kk = g * 8 + p * 2;
                float x0 = Tb[tk_s[kk] * 128 + cbuild] + Vb[(size_t)(k0 + kk) * 128 + cbuild];
                float x1 = Tb[tk_s[kk + 1] * 128 + cbuild] + Vb[(size_t)(k0 + kk + 1) * 128 + cbuild];
                hh[p] = bfpair(x0, x1, ll[p]);
            }
            int off = (t * 64 + g * 16) ^ ((t & 7) << 4);
            *(uint4v*)((char*)Mh + off) = (uint4v){hh[0], hh[1], hh[2], hh[3]};
            *(uint4v*)((char*)Ml + off) = (uint4v){ll[0], ll[1], ll[2], ll[3]};
        }
        // ---- scores + wave-parallel online softmax (2 q-rows/thread) ----
        #pragma unroll
        for (int rr = 0; rr < 2; ++rr) {
            int q = qr + rr * 32;
            int qg = q0 + q;
            int tq = tq_s[q];
            f32x4 gqk = *(const f32x4*)&Gqk[(size_t)qg * SEQ + k0 + kb4];
            f32x4 gtk = *(const f32x4*)&Gtk[(size_t)tq * SEQ + k0 + kb4];
            float s[4];
            #pragma unroll
            for (int j = 0; j < 4; ++j) {
                int kg = k0 + kb4 + j;
                int tkv = tk_s[kb4 + j];
                s[j] = (kg <= qg)
                     ? c1 * (gqk[j] + gtk[j] + Gtt[tq * 128 + tkv] + Gqt[qg * 128 + tkv])
                     : NEG_INF;
            }
            float tmax = fmaxf(fmaxf(s[0], s[1]), fmaxf(s[2], s[3]));
            tmax = fmaxf(tmax, __shfl_xor(tmax, 1));
            tmax = fmaxf(tmax, __shfl_xor(tmax, 2));
            tmax = fmaxf(tmax, __shfl_xor(tmax, 4));
            float m_old = m_s[q];
            float mnew = fmaxf(m_old, tmax);
            float p0 = __expf(s[0] - mnew), p1 = __expf(s[1] - mnew);
            float p2 = __expf(s[2] - mnew), p3 = __expf(s[3] - mnew);
            float lsum = p0 + p1 + p2 + p3;
            lsum += __shfl_xor(lsum, 1);
            lsum += __shfl_xor(lsum, 2);
            lsum += __shfl_xor(lsum, 4);
            unsigned int l01, l23;
            unsigned int h01 = bfpair(p0, p1, l01);
            unsigned int h23 = bfpair(p2, p3, l23);
            int off = (q * 64 + kb4 * 2) ^ ((q & 7) << 4);
            *(uint2v*)((char*)Ph + off) = (uint2v){h01, h23};
            *(uint2v*)((char*)Pl + off) = (uint2v){l01, l23};
            if ((t & 7) == 0) {
                float rs = __expf(m_old - mnew);
                m_s[q] = mnew;
                l_s[q] = l_s[q] * rs + lsum;
                rs_s[q] = rs;
            }
        }
        __syncthreads();
        // ---- rescale acc + MFMA PV ----
        short8 pah[4], pal[4];
        f32x4 rsv[4];
        #pragma unroll
        for (int qf = 0; qf < 4; ++qf) {
            int row = qf * 16 + lr;
            int off = (row * 64 + kbyte) ^ ((row & 7) << 4);
            pah[qf] = *(const short8*)((const char*)Ph + off);
            pal[qf] = *(const short8*)((const char*)Pl + off);
            rsv[qf] = *(const f32x4*)&rs_s[qf * 16 + ((lane >> 4) << 2)];
        }
        #pragma unroll
        for (int qf = 0; qf < 4; ++qf)
            #pragma unroll
            for (int cf = 0; cf < 4; ++cf)
                #pragma unroll
                for (int j = 0; j < 4; ++j)
                    acc[qf][cf][j] *= rsv[qf][j];
        #pragma unroll
        for (int cf = 0; cf < 4; ++cf) {
            int col = wave * 64 + cf * 16 + lr;
            int off = (col * 64 + kbyte) ^ ((col & 7) << 4);
            short8 bh = *(const short8*)((const char*)Mh + off);
            short8 bl = *(const short8*)((const char*)Ml + off);
            #pragma unroll
            for (int qf = 0; qf < 4; ++qf) {
                acc[qf][cf] = __builtin_amdgcn_mfma_f32_16x16x32_bf16(pah[qf], bh, acc[qf][cf], 0, 0, 0);
                acc[qf][cf] = __builtin_amdgcn_mfma_f32_16x16x32_bf16(pah[qf], bl, acc[qf][cf], 0, 0, 0);
                acc[qf][cf] = __builtin_amdgcn_mfma_f32_16x16x32_bf16(pal[qf], bh, acc[qf][cf], 0, 0, 0);
            }
        }
        __syncthreads();
    }
    // ---- epilogue: divide by l, write O ----
    #pragma unroll
    for (int qf = 0; qf < 4; ++qf) {
        f32x4 lv = *(const f32x4*)&l_s[qf * 16 + ((lane >> 4) << 2)];
        f32x4 inv;
        #pragma unroll
        for (int j = 0; j < 4; ++j) inv[j] = 1.0f / lv[j];
        #pragma unroll
        for (int j = 0; j < 4; ++j) {
            int row = q0 + qf * 16 + ((lane >> 4) << 2) + j;
            size_t base = ((size_t)b * SEQ + row) * 256 + wave * 64 + lr;
            #pragma unroll
            for (int cf = 0; cf < 4; ++cf)
                O[base + cf * 16] = acc[qf][cf][j] * inv[j];
        }
    }
}

// ------------------------------------------------------------------
// Stage 2: one 256-thread workgroup per batch. (unchanged, proven)
// ------------------------------------------------------------------
__device__ __forceinline__ float blk_reduce_max(float v, float* red, int t)
{
    red[t] = v; __syncthreads();
    #pragma unroll
    for (int s = 128; s >= 1; s >>= 1) {
        if (t < s) red[t] = fmaxf(red[t], red[t + s]);
        __syncthreads();
    }
    float r = red[0]; __syncthreads(); return r;
}
__device__ __forceinline__ float blk_reduce_sum(float v, float* red, int t)
{
    red[t] = v; __syncthreads();
    #pragma unroll
    for (int s = 128; s >= 1; s >>= 1) {
        if (t < s) red[t] += red[t + s];
        __syncthreads();
    }
    float r = red[0]; __syncthreads(); return r;
}

__global__ __launch_bounds__(256) void stage2(
    const int* __restrict__ tok,
    const float* __restrict__ emb, const float* __restrict__ pos,
    const float* __restrict__ Gtt, const float* __restrict__ Gtk,
    const float* __restrict__ Gqt, const float* __restrict__ Gqk,
    const float* __restrict__ Tv,  const float* __restrict__ Vp,
    const float* __restrict__ WQ2,
    const float* __restrict__ TxK, const float* __restrict__ PxK,
    const float* __restrict__ TxV, const float* __restrict__ PxV,
    const float* __restrict__ O,
    const float* __restrict__ beta1, const float* __restrict__ beta2,
    const float* __restrict__ beta_out,
    float* __restrict__ out)
{
    const int b = blockIdx.x;
    const int t = threadIdx.x;
    const float c1 = beta1[0] * 1.12890625f;
    const float c2 = beta2[0] * 289.0f;
    const float co = beta_out[0] * 70.09279563550022f;

    __shared__ float a_s[SEQ];
    __shared__ float red_s[256];
    __shared__ float w_s[VOC];
    __shared__ float z_s[DM];
    __shared__ float q2_s[VOC];
    __shared__ float y2_s[VOC];

    const int* tokb = tok + (size_t)b * SEQ;
    const int tq = tokb[SEQ - 1];

    float lmax = NEG_INF;
    for (int i = t; i < SEQ; i += 256) {
        int tk = tokb[i];
        float s = c1 * (Gtt[tq * 128 + tk] + Gtk[(size_t)tq * SEQ + i]
                      + Gqt[(SEQ - 1) * 128 + tk] + Gqk[(size_t)(SEQ - 1) * SEQ + i]);
        a_s[i] = s;
        lmax = fmaxf(lmax, s);
    }
    float m = blk_reduce_max(lmax, red_s, t);
    float lsum = 0.f;
    for (int i = t; i < SEQ; i += 256) {
        float e = __expf(a_s[i] - m);
        a_s[i] = e;
        lsum += e;
    }
    float l = blk_reduce_sum(lsum, red_s, t);
    float inv = 1.f / l;
    for (int i = t; i < SEQ; i += 256) a_s[i] *= inv;

    if (t < VOC) w_s[t] = 0.f;
    __syncthreads();
    for (int i = t; i < SEQ; i += 256) {
        int tk = tokb[i];
        atomicAdd(&w_s[tk], a_s[i]);
    }
    __syncthreads();

    float accz[9];
    #pragma unroll
    for (int j = 0; j < 9; ++j) accz[j] = 0.f;
    for (int k = 0; k < SEQ; ++k) {
        float a = a_s[k];
        const float* vr = Vp + (size_t)k * DM;
        #pragma unroll
        for (int j = 0; j < 9; ++j) {
            int d = t + j * 256;
            if (d < DM) accz[j] += a * vr[d];
        }
    }
    for (int tt = 0; tt < VOC; ++tt) {
        float w = w_s[tt];
        const float* tr = Tv + (size_t)tt * DM;
        #pragma unroll
        for (int j = 0; j < 9; ++j) {
            int d = t + j * 256;
            if (d < DM) accz[j] += w * tr[d];
        }
    }
    #pragma unroll
    for (int j = 0; j < 9; ++j) {
        int d = t + j * 256;
        if (d < DM) {
            float x = (d < VOC) ? emb[tq * VOC + d]
                                : pos[(size_t)(SEQ - 1) * SEQ + (d - VOC)];
            z_s[d] = x + accz[j];
        }
    }
    __syncthreads();

    if (t < VOC) {
        float s = 0.f;
        for (int d = 0; d < DM; ++d) s += z_s[d] * WQ2[(size_t)d * VOC + t];
        q2_s[t] = c2 * s;
    }
    __syncthreads();

    float lmax2 = NEG_INF;
    for (int i = t; i < SEQ; i += 256) {
        int tk = tokb[i];
        const float* orow = O + ((size_t)b * SEQ + i) * 256;
        const float* xk = TxK + tk * VOC;
        const float* pk = PxK + (size_t)i * VOC;
        float s = 0.f;
        for (int v = 0; v < VOC; ++v) s += q2_s[v] * (xk[v] + pk[v] + orow[v]);
        a_s[i] = s;
        lmax2 = fmaxf(lmax2, s);
    }
    float m2 = blk_reduce_max(lmax2, red_s, t);
    float lsum2 = 0.f;
    for (int i = t; i < SEQ; i += 256) {
        float e = __expf(a_s[i] - m2);
        a_s[i] = e;
        lsum2 += e;
    }
    float l2 = blk_reduce_sum(lsum2, red_s, t);
    float inv2 = 1.f / l2;
    for (int i = t; i < SEQ; i += 256) a_s[i] *= inv2;
    __syncthreads();

    if (t < VOC) {
        float y = 0.f;
        for (int s2 = 0; s2 < SEQ; ++s2) {
            int tk = tokb[s2];
            y += a_s[s2] * (TxV[tk * VOC + t] + PxV[(size_t)s2 * VOC + t]
                          + O[((size_t)b * SEQ + s2) * 256 + 128 + t]);
        }
        y2_s[t] = y;
    }
    __syncthreads();

    if (t < VOC) {
        float g = 0.f;
        for (int v = 0; v < VOC; ++v) g += y2_s[v] * emb[t * VOC + v];
        out[(size_t)b * VOC + t] = co * g;
    }
}

// ------------------------------------------------------------------
extern "C" void kernel_launch(void* const* d_in, const int* in_sizes, int n_in,
                              void* d_out, int out_size, void* d_ws, size_t ws_size,
                              hipStream_t stream)
{
    const int* tok = (const int*)d_in[0];
    const float* emb = (const float*)d_in[1];
    const float* pos = (const float*)d_in[2];
    const float* WQ1 = (const float*)d_in[3];
    const float* WK1 = (const float*)d_in[4];
    const float* WV1 = (const float*)d_in[5];
    const float* WQ2 = (const float*)d_in[6];
    const float* WK2 = (const float*)d_in[7];
    const float* WV2 = (const float*)d_in[8];
    const float* beta1 = (const float*)d_in[9];
    const float* beta2 = (const float*)d_in[10];
    const float* beta_out = (const float*)d_in[11];
    float* out = (float*)d_out;

    if (ws_size < 178651136ull) return;   // ~170.4 MB needed (proven available)

    char* wsb = (char*)d_ws;
    #define MB_(x) ((size_t)(x) * 1048576ull)
    // Split-buffer region: aliased with O (all splits dead before attn runs)
    unsigned short* posH = (unsigned short*)(wsb + MB_(0));
    unsigned short* posL = (unsigned short*)(wsb + MB_(8));
    unsigned short* WTH  = (unsigned short*)(wsb + MB_(16));
    unsigned short* WTL  = (unsigned short*)(wsb + MB_(25));
    unsigned short* QpH  = (unsigned short*)(wsb + MB_(34));
    unsigned short* QpL  = (unsigned short*)(wsb + MB_(42));
    unsigned short* KpH  = (unsigned short*)(wsb + MB_(50));
    unsigned short* KpL  = (unsigned short*)(wsb + MB_(58));
    unsigned short* VpH  = (unsigned short*)(wsb + MB_(66));
    unsigned short* VpL  = (unsigned short*)(wsb + MB_(75));
    unsigned short* TqH  = (unsigned short*)(wsb + MB_(84));
    unsigned short* TqL  = (unsigned short*)(wsb + MB_(84) + 524288);
    unsigned short* TkH  = (unsigned short*)(wsb + MB_(85));
    unsigned short* TkL  = (unsigned short*)(wsb + MB_(85) + 524288);
    float* O = (float*)(wsb + MB_(0));    // 128 MB, aliases the splits

    float* fp = (float*)(wsb + MB_(128));
    auto take = [&](size_t n) { float* p = fp; fp += n; return p; };
    float* Vp  = take((size_t)2048 * 2176);
    float* Gqk = take((size_t)2048 * 2048);
    float* Gtk = take((size_t)128 * 2048);
    float* Gqt = take((size_t)2048 * 128);
    float* Gtt = take((size_t)128 * 128);
    float* Tq  = take((size_t)128 * 2048);
    float* Tk  = take((size_t)128 * 2048);
    float* Tv  = take((size_t)128 * 2176);
    float* TxK = take((size_t)128 * 128);
    float* TxV = take((size_t)128 * 128);
    float* TvK = take((size_t)128 * 128);
    float* TvV = take((size_t)128 * 128);
    float* VpK = take((size_t)2048 * 128);
    float* VpV = take((size_t)2048 * 128);
    float* PxK = take((size_t)2048 * 128);
    float* PxV = take((size_t)2048 * 128);

    dim3 blk(256);

    // --- tiny token-table GEMMs (f32) ---
    hipLaunchKernelGGL((gemm_f32<0>), dim3(32, 2), blk, 0, stream, emb, 128, WQ1, 2048, Tq, 2048, 128, 2048, 128);
    hipLaunchKernelGGL((gemm_f32<0>), dim3(32, 2), blk, 0, stream, emb, 128, WK1, 2048, Tk, 2048, 128, 2048, 128);
    hipLaunchKernelGGL((gemm_f32<0>), dim3(34, 2), blk, 0, stream, emb, 128, WV1, 2176, Tv, 2176, 128, 2176, 128);
    hipLaunchKernelGGL((gemm_f32<0>), dim3(2, 2),  blk, 0, stream, emb, 128, WK2, 128, TxK, 128, 128, 128, 128);
    hipLaunchKernelGGL((gemm_f32<0>), dim3(2, 2),  blk, 0, stream, emb, 128, WV2, 128, TxV, 128, 128, 128, 128);

    // --- splits + big MFMA GEMMs ---
    hipLaunchKernelGGL(split_plain, dim3(4096), blk, 0, stream, pos, posH, posL, 1048576);
    hipLaunchKernelGGL(splitT, dim3(64, 64), blk, 0, stream, WQ1, 2048, 128, 2048, 2048, WTH, WTL);
    hipLaunchKernelGGL((gemm_nt_mfma<2>), dim3(16, 16), blk, 0, stream,
                       posH, posL, 2048, WTH, WTL, 2048, (float*)nullptr, QpH, QpL, 2048, 2048);
    hipLaunchKernelGGL(splitT, dim3(64, 64), blk, 0, stream, WK1, 2048, 128, 2048, 2048, WTH, WTL);
    hipLaunchKernelGGL((gemm_nt_mfma<2>), dim3(16, 16), blk, 0, stream,
                       posH, posL, 2048, WTH, WTL, 2048, (float*)nullptr, KpH, KpL, 2048, 2048);
    hipLaunchKernelGGL(splitT, dim3(64, 68), blk, 0, stream, WV1, 2176, 128, 2048, 2176, WTH, WTL);
    hipLaunchKernelGGL((gemm_nt_mfma<3>), dim3(17, 16), blk, 0, stream,
                       posH, posL, 2048, WTH, WTL, 2048, Vp, VpH, VpL, 2176, 2048);
    hipLaunchKernelGGL((gemm_nt_mfma<1>), dim3(16, 16), blk, 0, stream,
                       QpH, QpL, 2048, KpH, KpL, 2048, Gqk, (unsigned short*)nullptr, (unsigned short*)nullptr, 2048, 2048);
    hipLaunchKernelGGL(split_plain, dim3(256), blk, 0, stream, Tq, TqH, TqL, 65536);
    hipLaunchKernelGGL(split_plain, dim3(256), blk, 0, stream, Tk, TkH, TkL, 65536);
    hipLaunchKernelGGL((gemm_nt_mfma<1>), dim3(16, 1), blk, 0, stream,
                       TqH, TqL, 2048, KpH, KpL, 2048, Gtk, (unsigned short*)nullptr, (unsigned short*)nullptr, 2048, 2048);
    hipLaunchKernelGGL((gemm_nt_mfma<1>), dim3(1, 16), blk, 0, stream,
                       QpH, QpL, 2048, TkH, TkL, 2048, Gqt, (unsigned short*)nullptr, (unsigned short*)nullptr, 128, 2048);
    hipLaunchKernelGGL((gemm_nt_mfma<1>), dim3(1, 1), blk, 0, stream,
                       TqH, TqL, 2048, TkH, TkL, 2048, Gtt, (unsigned short*)nullptr, (unsigned short*)nullptr, 128, 2048);
    hipLaunchKernelGGL(splitT, dim3(64, 4), blk, 0, stream, WK2, 128, 128, 2048, 128, WTH, WTL);
    hipLaunchKernelGGL((gemm_nt_mfma<1>), dim3(1, 16), blk, 0, stream,
                       posH, posL, 2048, WTH, WTL, 2048, PxK, (unsigned short*)nullptr, (unsigned short*)nullptr, 128, 2048);
    hipLaunchKernelGGL(splitT, dim3(64, 4), blk, 0, stream, WV2, 128, 128, 2048, 128, WTH, WTL);
    hipLaunchKernelGGL((gemm_nt_mfma<1>), dim3(1, 16), blk, 0, stream,
                       posH, posL, 2048, WTH, WTL, 2048, PxV, (unsigned short*)nullptr, (unsigned short*)nullptr, 128, 2048);
    hipLaunchKernelGGL(splitT, dim3(68, 4), blk, 0, stream, WK2, 128, 0, 2176, 128, WTH, WTL);
    hipLaunchKernelGGL((gemm_nt_mfma<1>), dim3(1, 16), blk, 0, stream,
                       VpH, VpL, 2176, WTH, WTL, 2176, VpK, (unsigned short*)nullptr, (unsigned short*)nullptr, 128, 2176);
    hipLaunchKernelGGL(splitT, dim3(68, 4), blk, 0, stream, WV2, 128, 0, 2176, 128, WTH, WTL);
    hipLaunchKernelGGL((gemm_nt_mfma<1>), dim3(1, 16), blk, 0, stream,
                       VpH, VpL, 2176, WTH, WTL, 2176, VpV, (unsigned short*)nullptr, (unsigned short*)nullptr, 128, 2176);
    hipLaunchKernelGGL((gemm_f32<0>), dim3(2, 2), blk, 0, stream, Tv, 2176, WK2, 128, TvK, 128, 128, 128, 2176);
    hipLaunchKernelGGL((gemm_f32<0>), dim3(2, 2), blk, 0, stream, Tv, 2176, WV2, 128, TvV, 128, 128, 128, 2176);

    // --- attention core (writes O; splits region is dead by now) ---
    hipLaunchKernelGGL(attn_mfma, dim3(32, 64), blk, 0, stream,
                       tok, Gtt, Gtk, Gqt, Gqk, TvK, TvV, VpK, VpV, beta1, O);

    // --- stage 2 ---
    hipLaunchKernelGGL(stage2, dim3(64), blk, 0, stream,
                       tok, emb, pos, Gtt, Gtk, Gqt, Gqk, Tv, Vp, WQ2,
                       TxK, PxK, TxV, PxV, O, beta1, beta2, beta_out, out);
}

// Round 4
// 2670.699 us; speedup vs baseline: 3.7774x; 2.0547x over previous
//
#include <hip/hip_runtime.h>
#include <cmath>

#define SEQ 2048
#define NB 64
#define VOC 128
#define DM 2176
#define NEG_INF -1e30f

typedef __attribute__((ext_vector_type(8))) short short8;
typedef __attribute__((ext_vector_type(4))) float f32x4;
typedef __attribute__((ext_vector_type(4))) unsigned int uint4v;
typedef __attribute__((ext_vector_type(2))) unsigned int uint2v;

// ---------- bf16 split helpers (hi = truncation, lo = remainder) ----------
__device__ __forceinline__ void splitf(float x, unsigned short& h, unsigned short& l) {
    unsigned int u = __float_as_uint(x);
    h = (unsigned short)(u >> 16);
    float d = x - __uint_as_float(u & 0xFFFF0000u);
    l = (unsigned short)(__float_as_uint(d) >> 16);
}
__device__ __forceinline__ unsigned int bfpair(float x0, float x1, unsigned int& lopair) {
    unsigned int u0 = __float_as_uint(x0), u1 = __float_as_uint(x1);
    float d0 = x0 - __uint_as_float(u0 & 0xFFFF0000u);
    float d1 = x1 - __uint_as_float(u1 & 0xFFFF0000u);
    lopair = (__float_as_uint(d0) >> 16) | (__float_as_uint(d1) & 0xFFFF0000u);
    return (u0 >> 16) | (u1 & 0xFFFF0000u);
}

// ------------------------------------------------------------------
// Naive tiled f32 GEMM (tiny GEMMs only). C[M,N] = A[M,K] @ B[K,N].
// ------------------------------------------------------------------
template<int TB>
__global__ __launch_bounds__(256) void gemm_f32(
    const float* __restrict__ A, int lda,
    const float* __restrict__ B, int ldb,
    float* __restrict__ C, int ldc,
    int M, int N, int K)
{
    __shared__ float As[16][64];
    __shared__ float Bs[16][65];
    const int bm = blockIdx.y * 64;
    const int bn = blockIdx.x * 64;
    const int t  = threadIdx.x;
    const int tx = t & 15, ty = t >> 4;
    float acc[4][4] = {};
    for (int k0 = 0; k0 < K; k0 += 16) {
        #pragma unroll
        for (int i = 0; i < 4; ++i) {
            int m = (t >> 4) + 16 * i;
            int k = t & 15;
            As[k][m] = A[(size_t)(bm + m) * lda + k0 + k];
        }
        if (TB == 0) {
            #pragma unroll
            for (int i = 0; i < 4; ++i) {
                int n = t & 63;
                int k = (t >> 6) + 4 * i;
                Bs[k][n] = B[(size_t)(k0 + k) * ldb + bn + n];
            }
        } else {
            #pragma unroll
            for (int i = 0; i < 4; ++i) {
                int k = t & 15;
                int n = (t >> 4) + 16 * i;
                Bs[k][n] = B[(size_t)(bn + n) * ldb + k0 + k];
            }
        }
        __syncthreads();
        #pragma unroll
        for (int kk = 0; kk < 16; ++kk) {
            float a[4], bb[4];
            #pragma unroll
            for (int i = 0; i < 4; ++i) a[i] = As[kk][ty * 4 + i];
            #pragma unroll
            for (int j = 0; j < 4; ++j) bb[j] = Bs[kk][tx * 4 + j];
            #pragma unroll
            for (int i = 0; i < 4; ++i)
                #pragma unroll
                for (int j = 0; j < 4; ++j)
                    acc[i][j] += a[i] * bb[j];
        }
        __syncthreads();
    }
    #pragma unroll
    for (int i = 0; i < 4; ++i) {
        size_t m = bm + ty * 4 + i;
        #pragma unroll
        for (int j = 0; j < 4; ++j)
            C[m * ldc + bn + tx * 4 + j] = acc[i][j];
    }
}

// ------------------------------------------------------------------
__global__ __launch_bounds__(256) void split_plain(
    const float* __restrict__ in, unsigned short* __restrict__ oh,
    unsigned short* __restrict__ ol, int n4)
{
    int i = blockIdx.x * 256 + threadIdx.x;
    if (i >= n4) return;
    f32x4 v = *(const f32x4*)(in + (size_t)i * 4);
    unsigned int h01, h23, l01, l23;
    h01 = bfpair(v[0], v[1], l01);
    h23 = bfpair(v[2], v[3], l23);
    *(uint2v*)(oh + (size_t)i * 4) = (uint2v){h01, h23};
    *(uint2v*)(ol + (size_t)i * 4) = (uint2v){l01, l23};
}

// ------------------------------------------------------------------
// Split + transpose: out[c][r] = in[(row0+r)*ld + c], r<NR, c<NC. out ld = NR.
// Grid (NR/32, NC/32), 256 threads.
// ------------------------------------------------------------------
__global__ __launch_bounds__(256) void splitT(
    const float* __restrict__ in, int ld, int row0,
    int NR, int NC,
    unsigned short* __restrict__ oh, unsigned short* __restrict__ ol)
{
    __shared__ float tile[32][33];
    const int r0 = blockIdx.x * 32, c0 = blockIdx.y * 32;
    const int t = threadIdx.x;
    const int x = t & 31, y = t >> 5;
    #pragma unroll
    for (int i = 0; i < 4; ++i) {
        int r = y + i * 8;
        tile[r][x] = in[(size_t)(row0 + r0 + r) * ld + c0 + x];
    }
    __syncthreads();
    #pragma unroll
    for (int i = 0; i < 4; ++i) {
        int c = y + i * 8;
        float v = tile[x][c];
        unsigned short h, l;
        splitf(v, h, l);
        size_t o = (size_t)(c0 + c) * NR + r0 + x;
        oh[o] = h; ol[o] = l;
    }
}

// ------------------------------------------------------------------
// Split-bf16 MFMA GEMM (NT): C[M,N] = (Ah+Al)[M,K] @ (Bh+Bl)[N,K]^T
// 3-term. Tile 128x128, BK=64, 4 waves. MODE bit0: f32 C; bit1: split Ch/Cl.
// ------------------------------------------------------------------
template<int MODE>
__global__ __launch_bounds__(256, 2) void gemm_nt_mfma(
    const unsigned short* __restrict__ Ah, const unsigned short* __restrict__ Al, int lda,
    const unsigned short* __restrict__ Bh, const unsigned short* __restrict__ Bl, int ldb,
    float* __restrict__ C, unsigned short* __restrict__ Ch, unsigned short* __restrict__ Cl,
    int ldc, int K)
{
    __shared__ __align__(16) unsigned short sAh[128 * 64], sAl[128 * 64];
    __shared__ __align__(16) unsigned short sBh[128 * 64], sBl[128 * 64];
    const int bm = blockIdx.y * 128, bn = blockIdx.x * 128;
    const int t = threadIdx.x;
    const int lane = t & 63, wave = t >> 6;
    const int wr = wave >> 1, wc = wave & 1;
    const int lr = lane & 15;

    f32x4 acc[4][4];
    #pragma unroll
    for (int i = 0; i < 4; ++i)
        #pragma unroll
        for (int j = 0; j < 4; ++j) acc[i][j] = (f32x4){0.f, 0.f, 0.f, 0.f};

    for (int k0 = 0; k0 < K; k0 += 64) {
        __syncthreads();
        #pragma unroll
        for (int i = 0; i < 4; ++i) {
            int idx = t + i * 256;
            int r = idx >> 3, kc = (idx & 7) * 8;
            int off = (r * 128 + kc * 2) ^ ((r & 7) << 4);
            size_t ga = (size_t)(bm + r) * lda + k0 + kc;
            size_t gb = (size_t)(bn + r) * ldb + k0 + kc;
            *(short8*)((char*)sAh + off) = *(const short8*)(Ah + ga);
            *(short8*)((char*)sAl + off) = *(const short8*)(Al + ga);
            *(short8*)((char*)sBh + off) = *(const short8*)(Bh + gb);
            *(short8*)((char*)sBl + off) = *(const short8*)(Bl + gb);
        }
        __syncthreads();
        #pragma unroll
        for (int ks = 0; ks < 2; ++ks) {
            const int kby = ks * 64 + ((lane >> 4) << 4);
            short8 ah[4], al[4];
            #pragma unroll
            for (int rf = 0; rf < 4; ++rf) {
                int row = wr * 64 + rf * 16 + lr;
                int off = (row * 128 + kby) ^ ((row & 7) << 4);
                ah[rf] = *(const short8*)((const char*)sAh + off);
                al[rf] = *(const short8*)((const char*)sAl + off);
            }
            #pragma unroll
            for (int cf = 0; cf < 4; ++cf) {
                int col = wc * 64 + cf * 16 + lr;
                int off = (col * 128 + kby) ^ ((col & 7) << 4);
                short8 bh = *(const short8*)((const char*)sBh + off);
                short8 bl = *(const short8*)((const char*)sBl + off);
                #pragma unroll
                for (int rf = 0; rf < 4; ++rf) {
                    acc[rf][cf] = __builtin_amdgcn_mfma_f32_16x16x32_bf16(ah[rf], bh, acc[rf][cf], 0, 0, 0);
                    acc[rf][cf] = __builtin_amdgcn_mfma_f32_16x16x32_bf16(ah[rf], bl, acc[rf][cf], 0, 0, 0);
                    acc[rf][cf] = __builtin_amdgcn_mfma_f32_16x16x32_bf16(al[rf], bh, acc[rf][cf], 0, 0, 0);
                }
            }
        }
    }
    #pragma unroll
    for (int rf = 0; rf < 4; ++rf) {
        #pragma unroll
        for (int j = 0; j < 4; ++j) {
            int row = bm + wr * 64 + rf * 16 + ((lane >> 4) << 2) + j;
            #pragma unroll
            for (int cf = 0; cf < 4; ++cf) {
                int col = bn + wc * 64 + cf * 16 + lr;
                float v = acc[rf][cf][j];
                size_t o = (size_t)row * ldc + col;
                if (MODE & 1) C[o] = v;
                if (MODE & 2) { unsigned short h, l; splitf(v, h, l); Ch[o] = h; Cl[o] = l; }
            }
        }
    }
}

// ------------------------------------------------------------------
// MFMA attention core (unchanged from round 3).
// ------------------------------------------------------------------
__global__ __launch_bounds__(256, 2) void attn_mfma(
    const int* __restrict__ tok,
    const float* __restrict__ Gtt, const float* __restrict__ Gtk,
    const float* __restrict__ Gqt, const float* __restrict__ Gqk,
    const float* __restrict__ TvK, const float* __restrict__ TvV,
    const float* __restrict__ VpK, const float* __restrict__ VpV,
    const float* __restrict__ beta1,
    float* __restrict__ O)
{
    const int b = blockIdx.y;
    const int q0 = blockIdx.x * 64;
    const int t = threadIdx.x;
    const int lane = t & 63, wave = t >> 6;
    const float c1 = beta1[0] * 1.12890625f;

    __shared__ __align__(16) unsigned short Mh[256 * 32], Ml[256 * 32];
    __shared__ __align__(16) unsigned short Ph[64 * 32], Pl[64 * 32];
    __shared__ __align__(16) float m_s[64], l_s[64], rs_s[64];
    __shared__ int tq_s[64], tk_s[32];

    if (t < 64) {
        tq_s[t] = tok[(size_t)b * SEQ + q0 + t];
        m_s[t] = NEG_INF;
        l_s[t] = 0.f;
    }
    f32x4 acc[4][4];
    #pragma unroll
    for (int i = 0; i < 4; ++i)
        #pragma unroll
        for (int j = 0; j < 4; ++j) acc[i][j] = (f32x4){0.f, 0.f, 0.f, 0.f};

    const int qr = t >> 3;
    const int kb4 = (t & 7) * 4;
    const int lr = lane & 15;
    const int kbyte = (lane >> 4) << 4;
    const int cbuild = t & 127;
    const float* Tb = (t < 128) ? TvK : TvV;
    const float* Vb = (t < 128) ? VpK : VpV;

    for (int k0 = 0; k0 <= q0 + 32; k0 += 32) {
        if (t < 32) tk_s[t] = tok[(size_t)b * SEQ + k0 + t];
        __syncthreads();
        #pragma unroll
        for (int g = 0; g < 4; ++g) {
            unsigned int hh[4], ll[4];
            #pragma unroll
            for (int p = 0; p < 4; ++p) {
                int kk = g * 8 + p * 2;
                float x0 = Tb[tk_s[kk] * 128 + cbuild] + Vb[(size_t)(k0 + kk) * 128 + cbuild];
                float x1 = Tb[tk_s[kk + 1] * 128 + cbuild] + Vb[(size_t)(k0 + kk + 1) * 128 + cbuild];
                hh[p] = bfpair(x0, x1, ll[p]);
            }
            int off = (t * 64 + g * 16) ^ ((t & 7) << 4);
            *(uint4v*)((char*)Mh + off) = (uint4v){hh[0], hh[1], hh[2], hh[3]};
            *(uint4v*)((char*)Ml + off) = (uint4v){ll[0], ll[1], ll[2], ll[3]};
        }
        #pragma unroll
        for (int rr = 0; rr < 2; ++rr) {
            int q = qr + rr * 32;
            int qg = q0 + q;
            int tq = tq_s[q];
            f32x4 gqk = *(const f32x4*)&Gqk[(size_t)qg * SEQ + k0 + kb4];
            f32x4 gtk = *(const f32x4*)&Gtk[(size_t)tq * SEQ + k0 + kb4];
            float s[4];
            #pragma unroll
            for (int j = 0; j < 4; ++j) {
                int kg = k0 + kb4 + j;
                int tkv = tk_s[kb4 + j];
                s[j] = (kg <= qg)
                     ? c1 * (gqk[j] + gtk[j] + Gtt[tq * 128 + tkv] + Gqt[qg * 128 + tkv])
                     : NEG_INF;
            }
            float tmax = fmaxf(fmaxf(s[0], s[1]), fmaxf(s[2], s[3]));
            tmax = fmaxf(tmax, __shfl_xor(tmax, 1));
            tmax = fmaxf(tmax, __shfl_xor(tmax, 2));
            tmax = fmaxf(tmax, __shfl_xor(tmax, 4));
            float m_old = m_s[q];
            float mnew = fmaxf(m_old, tmax);
            float p0 = __expf(s[0] - mnew), p1 = __expf(s[1] - mnew);
            float p2 = __expf(s[2] - mnew), p3 = __expf(s[3] - mnew);
            float lsum = p0 + p1 + p2 + p3;
            lsum += __shfl_xor(lsum, 1);
            lsum += __shfl_xor(lsum, 2);
            lsum += __shfl_xor(lsum, 4);
            unsigned int l01, l23;
            unsigned int h01 = bfpair(p0, p1, l01);
            unsigned int h23 = bfpair(p2, p3, l23);
            int off = (q * 64 + kb4 * 2) ^ ((q & 7) << 4);
            *(uint2v*)((char*)Ph + off) = (uint2v){h01, h23};
            *(uint2v*)((char*)Pl + off) = (uint2v){l01, l23};
            if ((t & 7) == 0) {
                float rs = __expf(m_old - mnew);
                m_s[q] = mnew;
                l_s[q] = l_s[q] * rs + lsum;
                rs_s[q] = rs;
            }
        }
        __syncthreads();
        short8 pah[4], pal[4];
        f32x4 rsv[4];
        #pragma unroll
        for (int qf = 0; qf < 4; ++qf) {
            int row = qf * 16 + lr;
            int off = (row * 64 + kbyte) ^ ((row & 7) << 4);
            pah[qf] = *(const short8*)((const char*)Ph + off);
            pal[qf] = *(const short8*)((const char*)Pl + off);
            rsv[qf] = *(const f32x4*)&rs_s[qf * 16 + ((lane >> 4) << 2)];
        }
        #pragma unroll
        for (int qf = 0; qf < 4; ++qf)
            #pragma unroll
            for (int cf = 0; cf < 4; ++cf)
                #pragma unroll
                for (int j = 0; j < 4; ++j)
                    acc[qf][cf][j] *= rsv[qf][j];
        #pragma unroll
        for (int cf = 0; cf < 4; ++cf) {
            int col = wave * 64 + cf * 16 + lr;
            int off = (col * 64 + kbyte) ^ ((col & 7) << 4);
            short8 bh = *(const short8*)((const char*)Mh + off);
            short8 bl = *(const short8*)((const char*)Ml + off);
            #pragma unroll
            for (int qf = 0; qf < 4; ++qf) {
                acc[qf][cf] = __builtin_amdgcn_mfma_f32_16x16x32_bf16(pah[qf], bh, acc[qf][cf], 0, 0, 0);
                acc[qf][cf] = __builtin_amdgcn_mfma_f32_16x16x32_bf16(pah[qf], bl, acc[qf][cf], 0, 0, 0);
                acc[qf][cf] = __builtin_amdgcn_mfma_f32_16x16x32_bf16(pal[qf], bh, acc[qf][cf], 0, 0, 0);
            }
        }
        __syncthreads();
    }
    #pragma unroll
    for (int qf = 0; qf < 4; ++qf) {
        f32x4 lv = *(const f32x4*)&l_s[qf * 16 + ((lane >> 4) << 2)];
        f32x4 inv;
        #pragma unroll
        for (int j = 0; j < 4; ++j) inv[j] = 1.0f / lv[j];
        #pragma unroll
        for (int j = 0; j < 4; ++j) {
            int row = q0 + qf * 16 + ((lane >> 4) << 2) + j;
            size_t base = ((size_t)b * SEQ + row) * 256 + wave * 64 + lr;
            #pragma unroll
            for (int cf = 0; cf < 4; ++cf)
                O[base + cf * 16] = acc[qf][cf][j] * inv[j];
        }
    }
}

// ------------------------------------------------------------------
// block reduce helpers
// ------------------------------------------------------------------
__device__ __forceinline__ float blk_reduce_max(float v, float* red, int t)
{
    red[t] = v; __syncthreads();
    #pragma unroll
    for (int s = 128; s >= 1; s >>= 1) {
        if (t < s) red[t] = fmaxf(red[t], red[t + s]);
        __syncthreads();
    }
    float r = red[0]; __syncthreads(); return r;
}
__device__ __forceinline__ float blk_reduce_sum(float v, float* red, int t)
{
    red[t] = v; __syncthreads();
    #pragma unroll
    for (int s = 128; s >= 1; s >>= 1) {
        if (t < s) red[t] += red[t + s];
        __syncthreads();
    }
    float r = red[0]; __syncthreads(); return r;
}

// ------------------------------------------------------------------
// Stage-2 P1: per-batch last-row attention weights a1[b][s] and
// token-binned weights w[b][t]. Grid (NB), 256 threads.
// ------------------------------------------------------------------
__global__ __launch_bounds__(256) void s2_p1(
    const int* __restrict__ tok,
    const float* __restrict__ Gtt, const float* __restrict__ Gtk,
    const float* __restrict__ Gqt, const float* __restrict__ Gqk,
    const float* __restrict__ beta1,
    float* __restrict__ a1g, float* __restrict__ wg)
{
    const int b = blockIdx.x;
    const int t = threadIdx.x;
    const float c1 = beta1[0] * 1.12890625f;

    __shared__ float a_s[SEQ];
    __shared__ float red_s[256];
    __shared__ float w_s[VOC];

    const int* tokb = tok + (size_t)b * SEQ;
    const int tq = tokb[SEQ - 1];

    float lmax = NEG_INF;
    for (int i = t; i < SEQ; i += 256) {
        int tk = tokb[i];
        float s = c1 * (Gtt[tq * 128 + tk] + Gtk[(size_t)tq * SEQ + i]
                      + Gqt[(SEQ - 1) * 128 + tk] + Gqk[(size_t)(SEQ - 1) * SEQ + i]);
        a_s[i] = s;
        lmax = fmaxf(lmax, s);
    }
    float m = blk_reduce_max(lmax, red_s, t);
    float lsum = 0.f;
    for (int i = t; i < SEQ; i += 256) {
        float e = __expf(a_s[i] - m);
        a_s[i] = e;
        lsum += e;
    }
    float l = blk_reduce_sum(lsum, red_s, t);
    float inv = 1.f / l;
    if (t < VOC) w_s[t] = 0.f;
    __syncthreads();
    for (int i = t; i < SEQ; i += 256) {
        float a = a_s[i] * inv;
        a1g[(size_t)b * SEQ + i] = a;
        atomicAdd(&w_s[tokb[i]], a);
    }
    __syncthreads();
    if (t < VOC) wg[b * VOC + t] = w_s[t];
}

// ------------------------------------------------------------------
// Stage-2 P2: q2[b][v] = TxQ[tq][v] + plq[v] + sum_s a1[s]*VpQ[s][v]
//                       + sum_t w[t]*TvQ[t][v].  Grid (NB), 256 threads.
// ------------------------------------------------------------------
__global__ __launch_bounds__(256) void s2_q2k(
    const int* __restrict__ tok, const float* __restrict__ a1g,
    const float* __restrict__ wg, const float* __restrict__ VpQ,
    const float* __restrict__ TvQ, const float* __restrict__ TxQ,
    const float* __restrict__ plq, float* __restrict__ q2)
{
    const int b = blockIdx.x, t = threadIdx.x;
    const int v = t & 127, half = t >> 7;
    __shared__ float red[256];
    const float* a1b = a1g + (size_t)b * SEQ;
    float acc = 0.f;
    for (int i = 0; i < 1024; ++i) {
        int s = half * 1024 + i;
        acc += a1b[s] * VpQ[(size_t)s * VOC + v];
    }
    if (half == 0) {
        const float* wb = wg + b * VOC;
        for (int tt = 0; tt < VOC; ++tt)
            acc += wb[tt] * TvQ[tt * VOC + v];
    }
    red[t] = acc; __syncthreads();
    if (t < VOC) {
        int tq = tok[(size_t)b * SEQ + SEQ - 1];
        q2[b * VOC + t] = red[t] + red[t + 128] + TxQ[tq * VOC + t] + plq[t];
    }
}

// ------------------------------------------------------------------
// Stage-2 P3a: split-flash over s. Grid (8, NB), 256 threads.
// part[b][c][0..127]=partial Y2 (scaled exp(m_c)), [128]=m_c, [129]=lsum_c.
// ------------------------------------------------------------------
__global__ __launch_bounds__(256) void s2_p3a(
    const int* __restrict__ tok, const float* __restrict__ q2,
    const float* __restrict__ TxK, const float* __restrict__ PxK,
    const float* __restrict__ TxV, const float* __restrict__ PxV,
    const float* __restrict__ O, const float* __restrict__ beta2,
    float* __restrict__ part)
{
    const int b = blockIdx.y, c = blockIdx.x, t = threadIdx.x;
    const int s0 = c * 256;
    const float c2 = beta2[0] * 289.0f;

    __shared__ float q2s[VOC];
    __shared__ int   toks[256];
    __shared__ float es[256];
    __shared__ float red[256];

    if (t < VOC) q2s[t] = q2[b * VOC + t] * c2;
    toks[t] = tok[(size_t)b * SEQ + s0 + t];
    __syncthreads();

    const int s = s0 + t;
    const float* ok = O + ((size_t)b * SEQ + s) * 256;
    const float* xk = TxK + toks[t] * VOC;
    const float* pk = PxK + (size_t)s * VOC;
    float dot = 0.f;
    #pragma unroll 8
    for (int v = 0; v < VOC; v += 4) {
        f32x4 a = *(const f32x4*)(ok + v);
        f32x4 x = *(const f32x4*)(xk + v);
        f32x4 p = *(const f32x4*)(pk + v);
        f32x4 q = *(const f32x4*)(q2s + v);
        dot += q[0] * (a[0] + x[0] + p[0]) + q[1] * (a[1] + x[1] + p[1])
             + q[2] * (a[2] + x[2] + p[2]) + q[3] * (a[3] + x[3] + p[3]);
    }
    float m = blk_reduce_max(dot, red, t);
    float e = __expf(dot - m);
    es[t] = e;
    float lsum = blk_reduce_sum(e, red, t);

    const int v = t & 127, half = t >> 7;
    float acc = 0.f;
    for (int i = 0; i < 128; ++i) {
        int si = half * 128 + i;
        float ee = es[si];
        acc += ee * (O[((size_t)b * SEQ + s0 + si) * 256 + 128 + v]
                   + TxV[toks[si] * VOC + v] + PxV[(size_t)(s0 + si) * VOC + v]);
    }
    red[t] = acc; __syncthreads();
    float* pb = part + ((size_t)b * 8 + c) * 132;
    if (t < VOC) pb[t] = red[t] + red[t + 128];
    if (t == 128) { pb[128] = m; pb[129] = lsum; }
}

// ------------------------------------------------------------------
// Stage-2 P3b: combine 8 partials + logits. Grid (NB), 128 threads.
// ------------------------------------------------------------------
__global__ __launch_bounds__(128) void s2_p3b(
    const float* __restrict__ part, const float* __restrict__ emb,
    const float* __restrict__ beta_out, float* __restrict__ out)
{
    const int b = blockIdx.x, t = threadIdx.x;
    const float co = beta_out[0] * 70.09279563550022f;
    __shared__ float y2[VOC];
    const float* pb = part + (size_t)b * 8 * 132;
    float M = NEG_INF;
    #pragma unroll
    for (int c = 0; c < 8; ++c) M = fmaxf(M, pb[c * 132 + 128]);
    float L = 0.f, y = 0.f;
    #pragma unroll
    for (int c = 0; c < 8; ++c) {
        float sc = __expf(pb[c * 132 + 128] - M);
        L += pb[c * 132 + 129] * sc;
        y += pb[c * 132 + t] * sc;
    }
    y2[t] = y / L;
    __syncthreads();
    float g = 0.f;
    #pragma unroll 8
    for (int v = 0; v < VOC; ++v) g += y2[v] * emb[t * VOC + v];
    out[(size_t)b * VOC + t] = co * g;
}

// ------------------------------------------------------------------
// plq[v] = pos[last] @ WQ2_bot.  Grid(1), 128 threads.
// ------------------------------------------------------------------
__global__ __launch_bounds__(128) void plq_k(
    const float* __restrict__ pos, const float* __restrict__ WQ2,
    float* __restrict__ plq)
{
    const int t = threadIdx.x;
    float acc = 0.f;
    for (int d = 0; d < SEQ; ++d)
        acc += pos[(size_t)(SEQ - 1) * SEQ + d] * WQ2[(size_t)(VOC + d) * VOC + t];
    plq[t] = acc;
}

// ------------------------------------------------------------------
extern "C" void kernel_launch(void* const* d_in, const int* in_sizes, int n_in,
                              void* d_out, int out_size, void* d_ws, size_t ws_size,
                              hipStream_t stream)
{
    const int* tok = (const int*)d_in[0];
    const float* emb = (const float*)d_in[1];
    const float* pos = (const float*)d_in[2];
    const float* WQ1 = (const float*)d_in[3];
    const float* WK1 = (const float*)d_in[4];
    const float* WV1 = (const float*)d_in[5];
    const float* WQ2 = (const float*)d_in[6];
    const float* WK2 = (const float*)d_in[7];
    const float* WV2 = (const float*)d_in[8];
    const float* beta1 = (const float*)d_in[9];
    const float* beta2 = (const float*)d_in[10];
    const float* beta_out = (const float*)d_in[11];
    float* out = (float*)d_out;

    if (ws_size < 178651136ull) return;

    char* wsb = (char*)d_ws;
    #define MB_(x) ((size_t)(x) * 1048576ull)
    // Split-buffer region: aliased with O (all splits dead before attn runs)
    unsigned short* posH = (unsigned short*)(wsb + MB_(0));
    unsigned short* posL = (unsigned short*)(wsb + MB_(8));
    unsigned short* WTH  = (unsigned short*)(wsb + MB_(16));
    unsigned short* WTL  = (unsigned short*)(wsb + MB_(25));
    unsigned short* QpH  = (unsigned short*)(wsb + MB_(34));
    unsigned short* QpL  = (unsigned short*)(wsb + MB_(42));
    unsigned short* KpH  = (unsigned short*)(wsb + MB_(50));
    unsigned short* KpL  = (unsigned short*)(wsb + MB_(58));
    unsigned short* VpH  = (unsigned short*)(wsb + MB_(66));
    unsigned short* VpL  = (unsigned short*)(wsb + MB_(75));
    unsigned short* TqH  = (unsigned short*)(wsb + MB_(84));
    unsigned short* TqL  = (unsigned short*)(wsb + MB_(84) + 524288);
    unsigned short* TkH  = (unsigned short*)(wsb + MB_(85));
    unsigned short* TkL  = (unsigned short*)(wsb + MB_(85) + 524288);
    float* O = (float*)(wsb + MB_(0));    // 128 MB, aliases the splits

    float* fp = (float*)(wsb + MB_(128));
    auto take = [&](size_t n) { float* p = fp; fp += n; return p; };
    float* Gqk = take((size_t)2048 * 2048);
    float* Gtk = take((size_t)128 * 2048);
    float* Gqt = take((size_t)2048 * 128);
    float* Gtt = take((size_t)128 * 128);
    float* Tq  = take((size_t)128 * 2048);
    float* Tk  = take((size_t)128 * 2048);
    float* Tv  = take((size_t)128 * 2176);
    float* TxK = take((size_t)128 * 128);
    float* TxV = take((size_t)128 * 128);
    float* TvK = take((size_t)128 * 128);
    float* TvV = take((size_t)128 * 128);
    float* VpK = take((size_t)2048 * 128);
    float* VpV = take((size_t)2048 * 128);
    float* PxK = take((size_t)2048 * 128);
    float* PxV = take((size_t)2048 * 128);
    float* VpQ = take((size_t)2048 * 128);
    float* TvQ = take((size_t)128 * 128);
    float* TxQ = take((size_t)128 * 128);
    float* plq = take((size_t)128);
    float* a1g = take((size_t)NB * 2048);
    float* wg  = take((size_t)NB * 128);
    float* q2  = take((size_t)NB * 128);
    float* part = take((size_t)NB * 8 * 132);

    dim3 blk(256);

    // --- tiny token-table GEMMs (f32) ---
    hipLaunchKernelGGL((gemm_f32<0>), dim3(32, 2), blk, 0, stream, emb, 128, WQ1, 2048, Tq, 2048, 128, 2048, 128);
    hipLaunchKernelGGL((gemm_f32<0>), dim3(32, 2), blk, 0, stream, emb, 128, WK1, 2048, Tk, 2048, 128, 2048, 128);
    hipLaunchKernelGGL((gemm_f32<0>), dim3(34, 2), blk, 0, stream, emb, 128, WV1, 2176, Tv, 2176, 128, 2176, 128);
    hipLaunchKernelGGL((gemm_f32<0>), dim3(2, 2),  blk, 0, stream, emb, 128, WK2, 128, TxK, 128, 128, 128, 128);
    hipLaunchKernelGGL((gemm_f32<0>), dim3(2, 2),  blk, 0, stream, emb, 128, WV2, 128, TxV, 128, 128, 128, 128);
    hipLaunchKernelGGL((gemm_f32<0>), dim3(2, 2),  blk, 0, stream, emb, 128, WQ2, 128, TxQ, 128, 128, 128, 128);
    hipLaunchKernelGGL(plq_k, dim3(1), dim3(128), 0, stream, pos, WQ2, plq);

    // --- splits + big MFMA GEMMs ---
    hipLaunchKernelGGL(split_plain, dim3(4096), blk, 0, stream, pos, posH, posL, 1048576);
    hipLaunchKernelGGL(splitT, dim3(64, 64), blk, 0, stream, WQ1, 2048, 128, 2048, 2048, WTH, WTL);
    hipLaunchKernelGGL((gemm_nt_mfma<2>), dim3(16, 16), blk, 0, stream,
                       posH, posL, 2048, WTH, WTL, 2048, (float*)nullptr, QpH, QpL, 2048, 2048);
    hipLaunchKernelGGL(splitT, dim3(64, 64), blk, 0, stream, WK1, 2048, 128, 2048, 2048, WTH, WTL);
    hipLaunchKernelGGL((gemm_nt_mfma<2>), dim3(16, 16), blk, 0, stream,
                       posH, posL, 2048, WTH, WTL, 2048, (float*)nullptr, KpH, KpL, 2048, 2048);
    hipLaunchKernelGGL(splitT, dim3(64, 68), blk, 0, stream, WV1, 2176, 128, 2048, 2176, WTH, WTL);
    hipLaunchKernelGGL((gemm_nt_mfma<2>), dim3(17, 16), blk, 0, stream,
                       posH, posL, 2048, WTH, WTL, 2048, (float*)nullptr, VpH, VpL, 2176, 2048);
    hipLaunchKernelGGL((gemm_nt_mfma<1>), dim3(16, 16), blk, 0, stream,
                       QpH, QpL, 2048, KpH, KpL, 2048, Gqk, (unsigned short*)nullptr, (unsigned short*)nullptr, 2048, 2048);
    hipLaunchKernelGGL(split_plain, dim3(256), blk, 0, stream, Tq, TqH, TqL, 65536);
    hipLaunchKernelGGL(split_plain, dim3(256), blk, 0, stream, Tk, TkH, TkL, 65536);
    hipLaunchKernelGGL((gemm_nt_mfma<1>), dim3(16, 1), blk, 0, stream,
                       TqH, TqL, 2048, KpH, KpL, 2048, Gtk, (unsigned short*)nullptr, (unsigned short*)nullptr, 2048, 2048);
    hipLaunchKernelGGL((gemm_nt_mfma<1>), dim3(1, 16), blk, 0, stream,
                       QpH, QpL, 2048, TkH, TkL, 2048, Gqt, (unsigned short*)nullptr, (unsigned short*)nullptr, 128, 2048);
    hipLaunchKernelGGL((gemm_nt_mfma<1>), dim3(1, 1), blk, 0, stream,
                       TqH, TqL, 2048, TkH, TkL, 2048, Gtt, (unsigned short*)nullptr, (unsigned short*)nullptr, 128, 2048);
    hipLaunchKernelGGL(splitT, dim3(64, 4), blk, 0, stream, WK2, 128, 128, 2048, 128, WTH, WTL);
    hipLaunchKernelGGL((gemm_nt_mfma<1>), dim3(1, 16), blk, 0, stream,
                       posH, posL, 2048, WTH, WTL, 2048, PxK, (unsigned short*)nullptr, (unsigned short*)nullptr, 128, 2048);
    hipLaunchKernelGGL(splitT, dim3(64, 4), blk, 0, stream, WV2, 128, 128, 2048, 128, WTH, WTL);
    hipLaunchKernelGGL((gemm_nt_mfma<1>), dim3(1, 16), blk, 0, stream,
                       posH, posL, 2048, WTH, WTL, 2048, PxV, (unsigned short*)nullptr, (unsigned short*)nullptr, 128, 2048);
    hipLaunchKernelGGL(splitT, dim3(68, 4), blk, 0, stream, WK2, 128, 0, 2176, 128, WTH, WTL);
    hipLaunchKernelGGL((gemm_nt_mfma<1>), dim3(1, 16), blk, 0, stream,
                       VpH, VpL, 2176, WTH, WTL, 2176, VpK, (unsigned short*)nullptr, (unsigned short*)nullptr, 128, 2176);
    hipLaunchKernelGGL(splitT, dim3(68, 4), blk, 0, stream, WV2, 128, 0, 2176, 128, WTH, WTL);
    hipLaunchKernelGGL((gemm_nt_mfma<1>), dim3(1, 16), blk, 0, stream,
                       VpH, VpL, 2176, WTH, WTL, 2176, VpV, (unsigned short*)nullptr, (unsigned short*)nullptr, 128, 2176);
    hipLaunchKernelGGL(splitT, dim3(68, 4), blk, 0, stream, WQ2, 128, 0, 2176, 128, WTH, WTL);
    hipLaunchKernelGGL((gemm_nt_mfma<1>), dim3(1, 16), blk, 0, stream,
                       VpH, VpL, 2176, WTH, WTL, 2176, VpQ, (unsigned short*)nullptr, (unsigned short*)nullptr, 128, 2176);
    hipLaunchKernelGGL((gemm_f32<0>), dim3(2, 2), blk, 0, stream, Tv, 2176, WK2, 128, TvK, 128, 128, 128, 2176);
    hipLaunchKernelGGL((gemm_f32<0>), dim3(2, 2), blk, 0, stream, Tv, 2176, WV2, 128, TvV, 128, 128, 128, 2176);
    hipLaunchKernelGGL((gemm_f32<0>), dim3(2, 2), blk, 0, stream, Tv, 2176, WQ2, 128, TvQ, 128, 128, 128, 2176);

    // --- attention core (writes O; splits region is dead by now) ---
    hipLaunchKernelGGL(attn_mfma, dim3(32, 64), blk, 0, stream,
                       tok, Gtt, Gtk, Gqt, Gqk, TvK, TvV, VpK, VpV, beta1, O);

    // --- stage 2 (parallel decomposition) ---
    hipLaunchKernelGGL(s2_p1, dim3(NB), blk, 0, stream,
                       tok, Gtt, Gtk, Gqt, Gqk, beta1, a1g, wg);
    hipLaunchKernelGGL(s2_q2k, dim3(NB), blk, 0, stream,
                       tok, a1g, wg, VpQ, TvQ, TxQ, plq, q2);
    hipLaunchKernelGGL(s2_p3a, dim3(8, NB), blk, 0, stream,
                       tok, q2, TxK, PxK, TxV, PxV, O, beta2, part);
    hipLaunchKernelGGL(s2_p3b, dim3(NB), dim3(128), 0, stream,
                       part, emb, beta_out, out);
}